// Round 3
// baseline (478.531 us; speedup 1.0000x reference)
//
#include <hip/hip_runtime.h>

typedef unsigned long long u64;
typedef unsigned int u32;

#define N_ROIS   10000
#define N_CLS    151
#define PRE_TOPN 6000
#define POST_TOPN 300
#define MAX_PER  64
#define NMS_TH   0.3f
#define SCORE_TH 0.05f

#define SORTN  8192             // pow2 >= CAP
#define CAP    6144             // candidate capacity (>=6000, tie slack), mult of CHUNK
#define BLOCKA 1024
#define CAPT   (CAP / BLOCKA)   // 6 staged keys per thread
#define CHUNK  512              // greedy chunk (matrix = 512x512 bits = 32 KB)
#define CWORDS (CHUNK / 32)     // 16
#define PADN   10240            // N_ROIS padded to BLOCKA multiple (ballot loops)

// dynamic-LDS layout (one workgroup per class), phase-overlapped:
//   select/sort: keys u64[8192] @0 (65536) | sbits u32[10000] @65536 (40000) -> 105536
//   greedy     : sbox f4[6144] @0 (98304) | sidx u32[6144] @98304 (24576)
//                supp u32[512*16] @122880 (32768) | kbox f4[300] @155648 (4800) -> 160448
#define SBITS_OFF  65536
#define SIDX_OFF   98304
#define SUPP_OFF   122880
#define KBOX_OFF   155648
#define SMEM_BYTES 160448

// IoU decision, IEEE f32 (no FMA contraction: "areaa+areab-inter" would fuse and
// could flip borderline iou<=0.3 decisions vs the XLA reference).
__device__ __forceinline__ bool suppresses(float4 a, float4 b)
{
#pragma clang fp contract(off)
    float areaa = (a.z - a.x + 1.f) * (a.w - a.y + 1.f);
    float areab = (b.z - b.x + 1.f) * (b.w - b.y + 1.f);
    float ix1 = fmaxf(a.x, b.x), iy1 = fmaxf(a.y, b.y);
    float ix2 = fminf(a.z, b.z), iy2 = fminf(a.w, b.w);
    float iw = fmaxf(ix2 - ix1 + 1.f, 0.f);
    float ih = fmaxf(iy2 - iy1 + 1.f, 0.f);
    float inter = iw * ih;
    float iou = inter / (areaa + areab - inter);
    return iou > NMS_TH;
}

__global__ __launch_bounds__(BLOCKA)
void nms_kernel(const float* __restrict__ scores,
                const float* __restrict__ boxes,
                float* __restrict__ dists,
                u64* __restrict__ rowkey)
{
    extern __shared__ __align__(16) char smem[];
    __shared__ int s_keep[POST_TOPN];
    __shared__ int s_nk, s_cnt;
    __shared__ int s_cnts[32];           // per-iteration search counters (no reset barrier)
    __shared__ u32 s_redu[BLOCKA / 64];
    __shared__ u32 s_alive[CWORDS];      // per-chunk phase-A survivor bits

    u64*    keys  = (u64*)smem;
    u32*    sbits = (u32*)(smem + SBITS_OFF);
    float4* sbox  = (float4*)smem;
    u32*    sidx  = (u32*)(smem + SIDX_OFF);
    u32*    supp  = (u32*)(smem + SUPP_OFF);
    float4* kbox  = (float4*)(smem + KBOX_OFF);

    const int c    = blockIdx.x + 1;     // classes 1..150 (class 0 = background, masked)
    const int tid  = threadIdx.x;
    const int lane = tid & 63, wid = tid >> 6;

    // ---- 1. score-bit column -> LDS + column max (f32 bits order-monotone for >=0)
    u32 lmax = 0;
    for (int r = tid; r < N_ROIS; r += BLOCKA) {
        u32 b = __float_as_uint(scores[r * N_CLS + c]);
        sbits[r] = b;
        lmax = b > lmax ? b : lmax;
    }
    for (int off = 32; off; off >>= 1) { u32 o = __shfl_down(lmax, off); lmax = o > lmax ? o : lmax; }
    if (lane == 0) s_redu[wid] = lmax;
    if (tid < 32) s_cnts[tid] = 0;
    __syncthreads();
    if (tid == 0) {
        u32 m = s_redu[0];
        for (int w = 1; w < BLOCKA / 64; ++w) m = s_redu[w] > m ? s_redu[w] : m;
        s_redu[0] = m;
        s_nk = 0;
        s_cnt = 0;
    }
    __syncthreads();
    if (s_redu[0] <= __float_as_uint(SCORE_TH)) return;  // col_valid false: column stays 0

    // ---- 2. exact kth bits: largest V with count(bits >= V) >= 6000
    //         (== top_k kth, then "score >= kth" active set, ties included)
    u32 lo = 0, hi = 0x7F800000u;
    int it = 0;
    while (hi - lo > 1u) {
        u32 mid = lo + ((hi - lo) >> 1);
        int cnt = 0;
        for (int r = tid; r < N_ROIS; r += BLOCKA) cnt += (sbits[r] >= mid) ? 1 : 0;
        for (int off = 32; off; off >>= 1) cnt += __shfl_down(cnt, off);
        if (lane == 0) atomicAdd(&s_cnts[it], cnt);
        __syncthreads();
        int total = s_cnts[it];
        if (total >= PRE_TOPN) lo = mid; else hi = mid;
        ++it;
    }
    const u32 V = lo;

    // ---- 3. compact {bits >= V} into keys, wave-aggregated (unordered; sort canonicalizes)
    for (int q = tid; q < SORTN; q += BLOCKA) keys[q] = 0;
    __syncthreads();
    for (int r = tid; r < PADN; r += BLOCKA) {
        bool pred = (r < N_ROIS) && (sbits[r] >= V);
        u64 ball = __ballot(pred);
        int base_ = 0;
        int cnt = __popcll(ball);
        if (lane == 0 && cnt) base_ = atomicAdd(&s_cnt, cnt);
        base_ = __shfl(base_, 0);
        if (pred) {
            int pos = base_ + __popcll(ball & ((1ull << lane) - 1ull));
            if (pos < SORTN)
                keys[pos] = ((u64)sbits[r] << 32) | (u64)(0xFFFFFFFFu - (u32)r); // desc score, asc row
        }
    }
    __syncthreads();
    const int Mfull = s_cnt;
    const int M = Mfull < CAP ? Mfull : CAP;

    // ---- 4. bitonic sort SORTN descending by full 64-bit key (conflict-free: contiguous b64)
    for (u32 k = 2; k <= SORTN; k <<= 1) {
        for (u32 j = k >> 1; j > 0; j >>= 1) {
            __syncthreads();
            for (u32 i = tid; i < SORTN; i += BLOCKA) {
                u32 ixj = i ^ j;
                if (ixj > i) {
                    u64 a = keys[i], b = keys[ixj];
                    if (((i & k) == 0) ? (a < b) : (a > b)) { keys[i] = b; keys[ixj] = a; }
                }
            }
        }
    }
    __syncthreads();

    // ---- 5. stage keys to regs, then overwrite union with sbox/sidx (gather boxes)
    u64 kreg[CAPT];
#pragma unroll
    for (int t = 0; t < CAPT; ++t) {
        int q = tid + t * BLOCKA;
        kreg[t] = (q < M) ? keys[q] : 0;
    }
    __syncthreads();
#pragma unroll
    for (int t = 0; t < CAPT; ++t) {
        int q = tid + t * BLOCKA;
        if (q < M) {
            u32 r = 0xFFFFFFFFu - (u32)kreg[t];
            if (r < N_ROIS) {
                sidx[q] = r;
                sbox[q] = *(const float4*)(boxes + ((size_t)r * N_CLS + c) * 4);
            } else {                      // unreachable (compaction emits real rows only)
                sidx[q] = 0u;
                sbox[q] = make_float4(-1e9f, -1e9f, -1e9f, -1e9f);
            }
        }
    }
    __syncthreads();

    // ---- 6. chunked greedy: phase A (vs kept list) -> pair matrix -> single-wave bit-sweep
    for (int base = 0; base < M; base += CHUNK) {
        int knum0 = s_nk;
        if (knum0 >= POST_TOPN) break;
        int chunkN = (M - base) < CHUNK ? (M - base) : CHUNK;

        // phase A: waves 0..7, one candidate per thread, test vs earlier keeps
        if (tid < CHUNK) {
            bool al = false;
            if (tid < chunkN) {
                al = true;
                float4 bq = sbox[base + tid];
                for (int j = 0; j < knum0; ++j)
                    if (suppresses(kbox[j], bq)) { al = false; break; }
            }
            u64 ball = __ballot(al);
            if (lane == 0) { s_alive[wid * 2] = (u32)ball; s_alive[wid * 2 + 1] = (u32)(ball >> 32); }
        }
        // zero matrix (independent of phase A writes)
        for (int w = tid; w < CHUNK * CWORDS; w += BLOCKA) supp[w] = 0;
        __syncthreads();

        // build "p suppresses q" bits (p<q, both phase-A-alive); 2 threads per row q
        {
            int q = tid >> 1;
            if (q < chunkN && ((s_alive[q >> 5] >> (q & 31)) & 1u)) {
                float4 bq = sbox[base + q];
                for (int p = (tid & 1); p < q; p += 2) {
                    if (!((s_alive[p >> 5] >> (p & 31)) & 1u)) continue;
                    if (suppresses(sbox[base + p], bq))
                        atomicOr(&supp[p * CWORDS + (q >> 5)], 1u << (q & 31));
                }
            }
        }
        __syncthreads();

        // sweep: wave 0; lanes 0..15 hold alive words; pick-first, AND-out its row
        if (wid == 0) {
            u32 aw = (lane < CWORDS) ? s_alive[lane] : 0u;
            int knum = knum0;
            while (knum < POST_TOPN) {
                u64 mask = __ballot(aw != 0u);
                if (!mask) break;
                int pl = __ffsll(mask) - 1;          // first lane with alive bits (uniform)
                u32 w = __shfl(aw, pl);
                int b = __ffs(w) - 1;
                int p = pl * 32 + b;                 // picked candidate (uniform)
                if (lane == 0) s_keep[knum] = base + p;
                ++knum;
                u32 row = supp[p * CWORDS + (lane & 15)];
                if (lane < CWORDS) aw &= ~row;       // suppress later chunk-mates
                if (lane == pl) aw &= ~(1u << b);    // consume the pick
            }
            if (lane == 0) s_nk = knum;
        }
        __syncthreads();
        // append kept boxes for the next chunk's phase A
        for (int j = knum0 + tid; j < s_nk; j += BLOCKA) kbox[j] = sbox[s_keep[j]];
        __syncthreads();
    }

    // ---- 7. scatter kept scores into dists (pre-zeroed) + per-row (score, ~class) atomic max
    for (int t = tid; t < s_nk; t += BLOCKA) {
        int q = s_keep[t];
        u32 r = sidx[q];
        float sc = scores[(size_t)r * N_CLS + c];
        dists[(size_t)r * N_CLS + c] = sc;
        u64 key = ((u64)__float_as_uint(sc) << 32) | (u64)(0xFFFFFFFFu - (u32)c);
        atomicMax(rowkey + r, key);   // max over classes; score ties -> lowest class (argmax)
    }
}

__global__ void zero2_kernel(float* __restrict__ a, int na, u64* __restrict__ b, int nb)
{
    int i = blockIdx.x * blockDim.x + threadIdx.x;
    int stride = gridDim.x * blockDim.x;
    for (int t = i; t < na; t += stride) a[t] = 0.f;
    for (int t = i; t < nb; t += stride) b[t] = 0ull;
}

#define B2T 1024
#define PER ((N_ROIS + B2T - 1) / B2T)   // 10 rows per thread, register-resident

__global__ __launch_bounds__(B2T)
void topk_kernel(const u64* __restrict__ rowkey, float* __restrict__ out)
{
    __shared__ u64 warr[B2T / 64];
    __shared__ u64 s_win;
    const int tid = threadIdx.x;
    const int lane = tid & 63, wid = tid >> 6;

    u64 loc[PER]; int lab[PER];
#pragma unroll
    for (int t = 0; t < PER; ++t) {
        int i = tid + t * B2T;
        u64 k = 0; int l = -1;
        if (i < N_ROIS) {
            u64 rk = rowkey[i];
            float v = __uint_as_float((u32)(rk >> 32));
            if (v > SCORE_TH) {
                k = (rk & 0xFFFFFFFF00000000ull) | (u64)(0xFFFFFFFFu - (u32)i); // score desc, row asc
                l = (int)(0xFFFFFFFFu - (u32)rk);                               // class label
            }
        }
        loc[t] = k; lab[t] = l;
    }

    float* out_s = out + (size_t)N_ROIS * N_CLS;
    float* out_i = out_s + MAX_PER;
    float* out_l = out_i + MAX_PER;

    for (int t = 0; t < MAX_PER; ++t) {
        u64 lm = 0;
#pragma unroll
        for (int s = 0; s < PER; ++s) lm = loc[s] > lm ? loc[s] : lm;
        for (int off = 32; off; off >>= 1) { u64 o = __shfl_down(lm, off); lm = o > lm ? o : lm; }
        if (lane == 0) warr[wid] = lm;
        __syncthreads();
        if (wid == 0) {
            u64 v = (lane < B2T / 64) ? warr[lane] : 0;
            for (int off = 8; off; off >>= 1) { u64 o = __shfl_down(v, off); v = o > v ? o : v; }
            if (lane == 0) s_win = v;
        }
        __syncthreads();
        u64 win = s_win;
        if (win == 0) {
            if (tid == 0) { out_s[t] = 0.f; out_i[t] = -1.f; out_l[t] = -1.f; }
        } else {
#pragma unroll
            for (int s = 0; s < PER; ++s) {
                if (loc[s] == win) {     // keys unique (row id encoded) -> exactly one winner
                    loc[s] = 0;
                    u32 i = 0xFFFFFFFFu - (u32)win;
                    out_s[t] = __uint_as_float((u32)(win >> 32));
                    out_i[t] = (float)i;
                    out_l[t] = (float)lab[s];
                }
            }
        }
        __syncthreads();
    }
}

extern "C" void kernel_launch(void* const* d_in, const int* in_sizes, int n_in,
                              void* d_out, int out_size, void* d_ws, size_t ws_size,
                              hipStream_t stream)
{
    const float* scores = (const float*)d_in[0];  // [10000, 151] f32
    const float* boxes  = (const float*)d_in[1];  // [10000, 151, 4] f32
    float* out = (float*)d_out;                   // dists[1510000] | scores[64] | inds[64] | labels[64]
    u64* rowkey = (u64*)d_ws;                     // [10000] packed (scorebits<<32)|~class

    // defensive: allow >64KB dynamic LDS (no-op/ignored error if not required on ROCm)
    (void)hipFuncSetAttribute((const void*)nms_kernel,
                              hipFuncAttributeMaxDynamicSharedMemorySize, SMEM_BYTES);

    zero2_kernel<<<1024, 256, 0, stream>>>(out, out_size, rowkey, N_ROIS);
    nms_kernel<<<N_CLS - 1, BLOCKA, SMEM_BYTES, stream>>>(scores, boxes, out, rowkey);
    topk_kernel<<<1, B2T, 0, stream>>>(rowkey, out);
}

// Round 4
// 281.151 us; speedup vs baseline: 1.7020x; 1.7020x over previous
//
#include <hip/hip_runtime.h>

typedef unsigned long long u64;
typedef unsigned int u32;

#define N_ROIS   10000
#define N_CLS    151
#define PRE_TOPN 6000
#define POST_TOPN 300
#define MAX_PER  64
#define NMS_TH   0.3f
#define SCORE_TH 0.05f

#define BLOCKA   1024
#define BAND_K   1024           // band target size (top-1024 first; rest lazily)
#define BANDCAP  2048           // band capacity (sort size)
#define CHUNK    512
#define CWORDS   (CHUNK / 32)   // 16
#define TROWS    10240          // scoresT padded row length

// dynamic-LDS layout (one workgroup per class); sbits persists, rest phase-local
#define SBITS_OFF 0             // u32[10000]           40000
#define KEYS_OFF  40000         // u64[2048]            16384
#define SBOX_OFF  56384         // float4[2048]         32768
#define SIDX_OFF  89152         // u32[2048]             8192
#define SUPP_OFF  97344         // u32[512*16]          32768
#define KBOX_OFF  130112        // float4[304]           4864
#define SMEM_BYTES 134976

// IoU decision, IEEE f32 (no FMA contraction: "areaa+areab-inter" would fuse and
// could flip borderline iou<=0.3 decisions vs the XLA reference).
__device__ __forceinline__ bool suppresses(float4 a, float4 b)
{
#pragma clang fp contract(off)
    float areaa = (a.z - a.x + 1.f) * (a.w - a.y + 1.f);
    float areab = (b.z - b.x + 1.f) * (b.w - b.y + 1.f);
    float ix1 = fmaxf(a.x, b.x), iy1 = fmaxf(a.y, b.y);
    float ix2 = fminf(a.z, b.z), iy2 = fminf(a.w, b.w);
    float iw = fmaxf(ix2 - ix1 + 1.f, 0.f);
    float ih = fmaxf(iy2 - iy1 + 1.f, 0.f);
    float inter = iw * ih;
    float iou = inter / (areaa + areab - inter);
    return iou > NMS_TH;
}

__global__ __launch_bounds__(BLOCKA)
void nms_kernel(const float* __restrict__ scores,
                const float* __restrict__ scoresT,
                const float* __restrict__ boxes,
                float* __restrict__ dists,
                u64* __restrict__ rowkey,
                int useT)
{
    extern __shared__ __align__(16) char smem[];
    __shared__ int s_cnts[32];          // rotating count slots (1 barrier per count)
    __shared__ int s_cc;                // compaction counter
    __shared__ int s_nk;
    __shared__ u32 s_redu[BLOCKA / 64];
    __shared__ u32 s_alive[CWORDS];
    __shared__ u32 s_rz[CWORDS];        // "row nonzero" bits (candidate suppresses someone)
    __shared__ int s_wpre[CWORDS];      // exclusive prefix of alive popcounts

    u32*    sbits = (u32*)(smem + SBITS_OFF);
    u64*    keys  = (u64*)(smem + KEYS_OFF);
    float4* sbox  = (float4*)(smem + SBOX_OFF);
    u32*    sidx  = (u32*)(smem + SIDX_OFF);
    u32*    supp  = (u32*)(smem + SUPP_OFF);
    float4* kbox  = (float4*)(smem + KBOX_OFF);

    const int c    = blockIdx.x + 1;    // classes 1..150 (class 0 = background, masked)
    const int tid  = threadIdx.x;
    const int lane = tid & 63, wid = tid >> 6;

    // ---- 1. score-bit column -> LDS (coalesced via scoresT when available) + column max
    u32 lmax = 0;
    if (useT) {
        const float* colp = scoresT + (size_t)c * TROWS;
        for (int r = tid; r < N_ROIS; r += BLOCKA) {
            u32 b = __float_as_uint(colp[r]);
            sbits[r] = b;
            lmax = b > lmax ? b : lmax;
        }
    } else {
        for (int r = tid; r < N_ROIS; r += BLOCKA) {
            u32 b = __float_as_uint(scores[(size_t)r * N_CLS + c]);
            sbits[r] = b;
            lmax = b > lmax ? b : lmax;
        }
    }
    for (int off = 32; off; off >>= 1) { u32 o = __shfl_down(lmax, off); lmax = o > lmax ? o : lmax; }
    if (lane == 0) s_redu[wid] = lmax;
    if (tid < 32) s_cnts[tid] = 0;
    __syncthreads();
    if (tid == 0) {
        u32 m = s_redu[0];
        for (int w = 1; w < BLOCKA / 64; ++w) m = s_redu[w] > m ? s_redu[w] : m;
        s_redu[0] = m;
        s_nk = 0;
    }
    __syncthreads();
    if (s_redu[0] <= __float_as_uint(SCORE_TH)) return;  // col_valid false: column stays 0

    // rotating-slot block count of {sbits >= mid}: ONE barrier per call.
    int slot = 0;
    auto count_ge = [&](u32 mid) -> int {
        int cnt = 0;
        const u64* sb2 = (const u64*)sbits;
        for (int r2 = tid; r2 < N_ROIS / 2; r2 += BLOCKA) {
            u64 two = sb2[r2];
            cnt += ((u32)two >= mid) ? 1 : 0;
            cnt += ((u32)(two >> 32) >= mid) ? 1 : 0;
        }
        for (int off = 32; off; off >>= 1) cnt += __shfl_down(cnt, off);
        if (lane == 0) atomicAdd(&s_cnts[slot & 31], cnt);
        __syncthreads();
        int total = s_cnts[slot & 31];
        if (tid == 0) s_cnts[(slot + 16) & 31] = 0;  // re-zero a slot 16 calls ahead
        ++slot;
        return total;
    };
    // largest V with count(>=V) >= target (count(>=0)=N_ROIS assumed >= target handled by caller)
    auto bin_search = [&](int target, u32* vOut, int* cntOut) {
        u32 lo = 0, hi = 0x7F800000u; int cntLo = N_ROIS;
        while (hi - lo > 1u) {
            u32 mid = lo + ((hi - lo) >> 1);
            int total = count_ge(mid);
            if (total >= target) { lo = mid; cntLo = total; } else hi = mid;
        }
        *vOut = lo; *cntOut = cntLo;
    };

    // ---- 2. lazy band loop: top-1024 band first; more bands only if keeps < 300
    u32 Vprev = 0x7F800000u;
    int Cprev = 0;
    u32 Vfloor = 0; int fcnt = 0, haveFloor = 0;
    int knum = 0;

    for (int band = 0; band < 12; ++band) {
        if (knum >= POST_TOPN) break;
        u32 Vlo; int cntAt;
        if (band == 0) {
            bin_search(BAND_K, &Vlo, &cntAt);
        } else {
            if (!haveFloor) { bin_search(PRE_TOPN, &Vfloor, &fcnt); haveFloor = 1; }
            if (Vprev <= Vfloor) break;            // all top-6000 (incl. ties) processed
            u32 v; int cl;
            bin_search(Cprev + BAND_K, &v, &cl);
            if (v <= Vfloor) { Vlo = Vfloor; cntAt = fcnt; }
            else             { Vlo = v;      cntAt = cl;  }
        }
        if (cntAt - Cprev > BANDCAP) {             // pathological tie mass: shrink band
            u32 v2 = Vlo + 1;
            if (v2 >= Vprev) break;
            Vlo = v2; cntAt = count_ge(v2);
            if (cntAt - Cprev > BANDCAP) break;
        }
        int Cband = cntAt - Cprev;
        if (Cband <= 0) { Vprev = Vlo; Cprev = cntAt; continue; }

        // ---- 3. compact band {Vlo <= bits < Vprev} into keys (unordered; sort canonicalizes)
        for (int q = tid; q < BANDCAP; q += BLOCKA) keys[q] = 0;
        if (tid == 0) s_cc = 0;
        __syncthreads();
        for (int r = tid; r < TROWS; r += BLOCKA) {
            bool pred = (r < N_ROIS) && (sbits[r] >= Vlo) && (sbits[r] < Vprev);
            u64 ball = __ballot(pred);
            int bpos = 0, bcnt = __popcll(ball);
            if (lane == 0 && bcnt) bpos = atomicAdd(&s_cc, bcnt);
            bpos = __shfl(bpos, 0);
            if (pred) {
                int pos = bpos + __popcll(ball & ((1ull << lane) - 1ull));
                if (pos < BANDCAP)
                    keys[pos] = ((u64)sbits[r] << 32) | (u64)(0xFFFFFFFFu - (u32)r);
            }
        }
        __syncthreads();
        int C = s_cc; if (C > BANDCAP) C = BANDCAP;

        // ---- 4. bitonic sort BANDCAP descending by full 64-bit key
        for (u32 k = 2; k <= BANDCAP; k <<= 1) {
            for (u32 j = k >> 1; j > 0; j >>= 1) {
                __syncthreads();
                for (u32 i = tid; i < BANDCAP; i += BLOCKA) {
                    u32 ixj = i ^ j;
                    if (ixj > i) {
                        u64 a = keys[i], b = keys[ixj];
                        if (((i & k) == 0) ? (a < b) : (a > b)) { keys[i] = b; keys[ixj] = a; }
                    }
                }
            }
        }
        __syncthreads();

        // ---- 5. gather candidate boxes
        for (int q = tid; q < C; q += BLOCKA) {
            u32 r = 0xFFFFFFFFu - (u32)keys[q];
            sidx[q] = r;
            sbox[q] = *(const float4*)(boxes + ((size_t)r * N_CLS + c) * 4);
        }
        __syncthreads();

        // ---- 6. chunked greedy: phase A (vs kept) -> pair matrix + rz -> batched sweep
        for (int base = 0; base < C && knum < POST_TOPN; base += CHUNK) {
            int chunkN = (C - base) < CHUNK ? (C - base) : CHUNK;
            int knum0 = knum;

            if (tid < CHUNK) {          // phase A: waves 0..7
                bool al = false;
                if (tid < chunkN) {
                    al = true;
                    float4 bq = sbox[base + tid];
                    for (int j = 0; j < knum0; ++j)
                        if (suppresses(kbox[j], bq)) { al = false; break; }
                }
                u64 ball = __ballot(al);
                if (lane == 0) { s_alive[wid * 2] = (u32)ball; s_alive[wid * 2 + 1] = (u32)(ball >> 32); }
            }
            if (tid < CWORDS) s_rz[tid] = 0;
            for (int w = tid; w < CHUNK * CWORDS; w += BLOCKA) supp[w] = 0;
            __syncthreads();

            {   // build "p suppresses q" (p<q, both alive); 2 threads per row q
                int q = tid >> 1;
                if (q < chunkN && ((s_alive[q >> 5] >> (q & 31)) & 1u)) {
                    float4 bq = sbox[base + q];
                    for (int p = (tid & 1); p < q; p += 2) {
                        if (!((s_alive[p >> 5] >> (p & 31)) & 1u)) continue;
                        if (suppresses(sbox[base + p], bq)) {
                            atomicOr(&supp[p * CWORDS + (q >> 5)], 1u << (q & 31));
                            atomicOr(&s_rz[p >> 5], 1u << (p & 31));
                        }
                    }
                }
            }
            __syncthreads();

            // sweep (wave 0): batch-keep zero-row candidates; LDS row read only for rz picks
            if (wid == 0) {
                u32 aw  = (lane < CWORDS) ? s_alive[lane] : 0u;
                u32 rzw = (lane < CWORDS) ? s_rz[lane] : 0u;
                const int budget = POST_TOPN - knum0;   // >= 1
                int truncTo = -1;
                while (true) {
                    u32 pz = aw & rzw;
                    u64 bal = __ballot(pz != 0u);
                    if (!bal) break;
                    int pl = __ffsll(bal) - 1;
                    u32 wv = __shfl(pz, pl);
                    int b = __ffs(wv) - 1;
                    int p = (pl << 5) + b;
                    int cb = (lane < pl) ? __popc(aw) : ((lane == pl) ? __popc(aw & ((1u << b) - 1u)) : 0);
                    for (int off = 32; off; off >>= 1) cb += __shfl_down(cb, off);
                    int before = __shfl(cb, 0);
                    if (before >= budget) { truncTo = budget; break; }   // cap hit before p
                    u32 row = supp[p * CWORDS + (lane & (CWORDS - 1))];  // p kept: apply row
                    if (lane < CWORDS) aw &= ~row;
                    if (lane == pl) { aw |= (1u << b); rzw &= ~(1u << b); }
                    if (before + 1 >= budget) { truncTo = budget; break; } // p was the 300th
                }
                if (truncTo < 0) {
                    int pcT = __popc(aw);
                    for (int off = 32; off; off >>= 1) pcT += __shfl_down(pcT, off);
                    if (__shfl(pcT, 0) > budget) truncTo = budget;
                }
                if (truncTo >= 0) {     // keep only first truncTo alive bits
                    int pcf = __popc(aw);
                    int inc = pcf;
                    for (int off = 1; off < 64; off <<= 1) { int o = __shfl_up(inc, off); if (lane >= off) inc += o; }
                    int ex = inc - pcf;
                    int need = truncTo - ex;
                    if (need <= 0) aw = 0;
                    else if (need < pcf) {
                        while (__popc(aw) > need) aw &= ~(1u << (31 - __clz(aw)));
                    }
                }
                if (lane < CWORDS) s_alive[lane] = aw;
                int pcf2 = __popc(aw);
                int inc2 = pcf2;
                for (int off = 1; off < 64; off <<= 1) { int o = __shfl_up(inc2, off); if (lane >= off) inc2 += o; }
                if (lane < CWORDS) s_wpre[lane] = inc2 - pcf2;
                int totF = __shfl(inc2, CWORDS - 1);
                if (lane == 0) s_nk = knum0 + totF;
            }
            __syncthreads();

            // commit: alive mask IS the kept set for this chunk
            if (tid < CHUNK) {
                int w = tid >> 5, b = tid & 31;
                u32 word = s_alive[w];
                if ((word >> b) & 1u) {
                    int rank = knum0 + s_wpre[w] + __popc(word & ((1u << b) - 1u));
                    int q = base + tid;
                    u32 r = sidx[q];
                    u32 sb = sbits[r];
                    kbox[rank] = sbox[q];
                    dists[(size_t)r * N_CLS + c] = __uint_as_float(sb);
                    atomicMax(rowkey + r, ((u64)sb << 32) | (u64)(0xFFFFFFFFu - (u32)c));
                }
            }
            __syncthreads();
            knum = s_nk;
        }

        Vprev = Vlo; Cprev = cntAt;
    }
}

__global__ __launch_bounds__(BLOCKA)
void transpose_kernel(const float* __restrict__ in, float* __restrict__ outT)
{
    __shared__ float tile[32][33];
    int tx = threadIdx.x & 31, ty = threadIdx.x >> 5;
    int rb = blockIdx.x * 32, cb = blockIdx.y * 32;
    int r = rb + ty, cc = cb + tx;
    tile[ty][tx] = (r < N_ROIS && cc < N_CLS) ? in[(size_t)r * N_CLS + cc] : 0.f;
    __syncthreads();
    int oc = cb + ty, orr = rb + tx;
    if (oc < N_CLS) outT[(size_t)oc * TROWS + orr] = tile[tx][ty];
}

__global__ void zero2_kernel(float* __restrict__ a, int na, u64* __restrict__ b, int nb)
{
    int i = blockIdx.x * blockDim.x + threadIdx.x;
    int stride = gridDim.x * blockDim.x;
    for (int t = i; t < na; t += stride) a[t] = 0.f;
    for (int t = i; t < nb; t += stride) b[t] = 0ull;
}

// top-64 via threshold search + compact + tiny sort (replaces 64 serial argmaxes)
__global__ __launch_bounds__(1024)
void topk_kernel(const u64* __restrict__ rowkey, float* __restrict__ out)
{
    __shared__ u32 shi[N_ROIS];
    __shared__ int s_cnts[32];
    __shared__ int s_cc;
    __shared__ u64 cand[128];
    const int tid = threadIdx.x, lane = tid & 63;

    if (tid < 32) s_cnts[tid] = 0;
    if (tid == 0) s_cc = 0;
    if (tid < 128) cand[tid] = 0;
    for (int i = tid; i < N_ROIS; i += 1024) {
        u64 rk = rowkey[i];
        u32 hb = (u32)(rk >> 32);
        shi[i] = (__uint_as_float(hb) > SCORE_TH) ? hb : 0u;   // invalid rows -> 0
    }
    __syncthreads();

    int slot = 0;
    u32 lo = 0, hi = 0x7F800000u;
    while (hi - lo > 1u) {
        u32 mid = lo + ((hi - lo) >> 1);
        int cnt = 0;
        const u64* s2 = (const u64*)shi;
        for (int r2 = tid; r2 < N_ROIS / 2; r2 += 1024) {
            u64 two = s2[r2];
            cnt += ((u32)two >= mid) ? 1 : 0;
            cnt += ((u32)(two >> 32) >= mid) ? 1 : 0;
        }
        for (int off = 32; off; off >>= 1) cnt += __shfl_down(cnt, off);
        if (lane == 0) atomicAdd(&s_cnts[slot & 31], cnt);
        __syncthreads();
        int total = s_cnts[slot & 31];
        if (tid == 0) s_cnts[(slot + 16) & 31] = 0;
        ++slot;
        if (total >= MAX_PER) lo = mid; else hi = mid;
    }
    u32 S = lo ? lo : 1u;    // lo==0: fewer than 64 valid -> take all valid

    for (int i = tid; i < TROWS; i += 1024) {
        bool pred = (i < N_ROIS) && (shi[i] >= S);
        u64 ball = __ballot(pred);
        int bpos = 0, bcnt = __popcll(ball);
        if (lane == 0 && bcnt) bpos = atomicAdd(&s_cc, bcnt);
        bpos = __shfl(bpos, 0);
        if (pred) {
            int pos = bpos + __popcll(ball & ((1ull << lane) - 1ull));
            if (pos < 128) cand[pos] = ((u64)shi[i] << 32) | (u64)(0xFFFFFFFFu - (u32)i);
        }
    }
    __syncthreads();
    for (u32 k = 2; k <= 128; k <<= 1) {
        for (u32 j = k >> 1; j > 0; j >>= 1) {
            __syncthreads();
            if (tid < 128) {
                u32 i = tid, ixj = i ^ j;
                if (ixj > i) {
                    u64 a = cand[i], b = cand[ixj];
                    if (((i & k) == 0) ? (a < b) : (a > b)) { cand[i] = b; cand[ixj] = a; }
                }
            }
        }
    }
    __syncthreads();

    float* out_s = out + (size_t)N_ROIS * N_CLS;
    float* out_i = out_s + MAX_PER;
    float* out_l = out_i + MAX_PER;
    if (tid < MAX_PER) {
        u64 kk = cand[tid];
        if (kk == 0) { out_s[tid] = 0.f; out_i[tid] = -1.f; out_l[tid] = -1.f; }
        else {
            u32 r = 0xFFFFFFFFu - (u32)kk;
            out_s[tid] = __uint_as_float((u32)(kk >> 32));
            out_i[tid] = (float)r;
            out_l[tid] = (float)(0xFFFFFFFFu - (u32)rowkey[r]);   // label from rowkey low word
        }
    }
}

extern "C" void kernel_launch(void* const* d_in, const int* in_sizes, int n_in,
                              void* d_out, int out_size, void* d_ws, size_t ws_size,
                              hipStream_t stream)
{
    const float* scores = (const float*)d_in[0];  // [10000, 151] f32
    const float* boxes  = (const float*)d_in[1];  // [10000, 151, 4] f32
    float* out = (float*)d_out;                   // dists[1510000] | scores[64] | inds[64] | labels[64]
    u64* rowkey = (u64*)d_ws;                     // [10000] packed (scorebits<<32)|~class

    size_t needT = 80000 + (size_t)N_CLS * TROWS * sizeof(float);
    int useT = (ws_size >= needT) ? 1 : 0;
    float* scoresT = (float*)((char*)d_ws + 80000);

    (void)hipFuncSetAttribute((const void*)nms_kernel,
                              hipFuncAttributeMaxDynamicSharedMemorySize, SMEM_BYTES);

    zero2_kernel<<<1024, 256, 0, stream>>>(out, out_size, rowkey, N_ROIS);
    if (useT) transpose_kernel<<<dim3(320, 5), BLOCKA, 0, stream>>>(scores, scoresT);
    nms_kernel<<<N_CLS - 1, BLOCKA, SMEM_BYTES, stream>>>(scores, scoresT, boxes, out, rowkey, useT);
    topk_kernel<<<1, 1024, 0, stream>>>(rowkey, out);
}

// Round 5
// 249.393 us; speedup vs baseline: 1.9188x; 1.1273x over previous
//
#include <hip/hip_runtime.h>

typedef unsigned long long u64;
typedef unsigned int u32;

#define N_ROIS   10000
#define N_CLS    151
#define PRE_TOPN 6000
#define POST_TOPN 300
#define MAX_PER  64
#define NMS_TH   0.3f
#define SCORE_TH 0.05f

#define BLOCKA   1024
#define NWAVES   (BLOCKA / 64)   // 16
#define BANDK    512             // band target size (typical: only band 0 runs)
#define BANDCAP  1024            // band capacity (tie slack)
#define CHUNK    640             // greedy chunk; typical band fits in ONE chunk
#define CWORDS   (CHUNK / 32)    // 20
#define TROWS    10240           // scoresT padded row length

// dynamic-LDS layout (one workgroup per class):
//   sbits u32[10000] @0      (40000)
//   keys  u64[1024] @40000   (8192)
//   rnk   u32[1024] @48192   (4096)
//   sbox  f4[1024]  @52288   (16384)
//   sidx  u32[1024] @68672   (4096)
//   supp  u32[640*20] @72768 (51200)
//   kbox  f4[304]   @123968  (4864)   -> 128832 total
#define KEYS_OFF  40000
#define RNK_OFF   48192
#define SBOX_OFF  52288
#define SIDX_OFF  68672
#define SUPP_OFF  72768
#define KBOX_OFF  123968
#define SMEM_BYTES 128832

// IoU decision, IEEE f32 (no FMA contraction: "areaa+areab-inter" would fuse and
// could flip borderline iou<=0.3 decisions vs the XLA reference).
__device__ __forceinline__ bool suppresses(float4 a, float4 b)
{
#pragma clang fp contract(off)
    float areaa = (a.z - a.x + 1.f) * (a.w - a.y + 1.f);
    float areab = (b.z - b.x + 1.f) * (b.w - b.y + 1.f);
    float ix1 = fmaxf(a.x, b.x), iy1 = fmaxf(a.y, b.y);
    float ix2 = fminf(a.z, b.z), iy2 = fminf(a.w, b.w);
    float iw = fmaxf(ix2 - ix1 + 1.f, 0.f);
    float ih = fmaxf(iy2 - iy1 + 1.f, 0.f);
    float inter = iw * ih;
    float iou = inter / (areaa + areab - inter);
    return iou > NMS_TH;
}

__global__ __launch_bounds__(BLOCKA)
void nms_kernel(const float* __restrict__ scores,
                const float* __restrict__ scoresT,
                const float* __restrict__ boxes,
                float* __restrict__ dists,
                u64* __restrict__ rowkey,
                int useT)
{
    extern __shared__ __align__(16) char smem[];
    __shared__ int s_cnts[32];          // rotating count slots (1 barrier per count)
    __shared__ int s_cc, s_nk;
    __shared__ u32 s_redu[NWAVES];
    __shared__ u32 s_alive[CWORDS], s_rz[CWORDS];
    __shared__ int s_wpre[CWORDS];
    __shared__ int s_wofs[NWAVES + 1];  // ordered-emit wave offsets (rare path)
    __shared__ int s_resume;

    u32*    sbits = (u32*)smem;
    u64*    keys  = (u64*)(smem + KEYS_OFF);
    u32*    rnk   = (u32*)(smem + RNK_OFF);
    float4* sbox  = (float4*)(smem + SBOX_OFF);
    u32*    sidx  = (u32*)(smem + SIDX_OFF);
    u32*    supp  = (u32*)(smem + SUPP_OFF);
    float4* kbox  = (float4*)(smem + KBOX_OFF);

    const int c    = blockIdx.x + 1;    // classes 1..150 (class 0 = background, masked)
    const int tid  = threadIdx.x;
    const int lane = tid & 63, wid = tid >> 6;

    // ---- 1. score-bit column -> LDS + column max (f32 bits order-monotone for >=0)
    u32 lmax = 0;
    if (useT) {
        const float* colp = scoresT + (size_t)c * TROWS;
        for (int r = tid; r < N_ROIS; r += BLOCKA) {
            u32 b = __float_as_uint(colp[r]); sbits[r] = b; lmax = b > lmax ? b : lmax;
        }
    } else {
        for (int r = tid; r < N_ROIS; r += BLOCKA) {
            u32 b = __float_as_uint(scores[(size_t)r * N_CLS + c]); sbits[r] = b; lmax = b > lmax ? b : lmax;
        }
    }
    for (int off = 32; off; off >>= 1) { u32 o = __shfl_down(lmax, off); lmax = o > lmax ? o : lmax; }
    if (lane == 0) s_redu[wid] = lmax;
    if (tid < 32) s_cnts[tid] = 0;
    __syncthreads();
    if (tid == 0) {
        u32 m = s_redu[0];
        for (int w = 1; w < NWAVES; ++w) m = s_redu[w] > m ? s_redu[w] : m;
        s_redu[0] = m; s_nk = 0;
    }
    __syncthreads();
    if (s_redu[0] <= __float_as_uint(SCORE_TH)) return;  // col_valid false: column stays 0

    // block count of {sbits >= v}: rotating slots, ONE barrier per call
    int slot = 0;
    auto count_ge = [&](u32 v) -> int {
        int cnt = 0;
        const u64* sb2 = (const u64*)sbits;
        for (int r2 = tid; r2 < N_ROIS / 2; r2 += BLOCKA) {
            u64 two = sb2[r2];
            cnt += ((u32)two >= v) ? 1 : 0;
            cnt += ((u32)(two >> 32) >= v) ? 1 : 0;
        }
        for (int off = 32; off; off >>= 1) cnt += __shfl_down(cnt, off);
        if (lane == 0 && cnt) atomicAdd(&s_cnts[slot & 31], cnt);
        __syncthreads();
        int total = s_cnts[slot & 31];
        if (tid == 0) s_cnts[(slot + 16) & 31] = 0;
        ++slot;
        return total;
    };

    // unordered compact {vlo <= bits < vhiX} into keys[pos0..] (rank pass canonicalizes order)
    auto compactRange = [&](u32 vlo, u32 vhiX, int pos0) -> int {
        if (tid == 0) s_cc = 0;
        __syncthreads();
        for (int r = tid; r < TROWS; r += BLOCKA) {
            bool pred = (r < N_ROIS) && (sbits[r] >= vlo) && (sbits[r] < vhiX);
            u64 ball = __ballot(pred);
            int bpos = 0, bcnt = __popcll(ball);
            if (lane == 0 && bcnt) bpos = atomicAdd(&s_cc, bcnt);
            bpos = __shfl(bpos, 0);
            if (pred) {
                int pos = pos0 + bpos + (int)__popcll(ball & ((1ull << lane) - 1ull));
                if (pos < BANDCAP)
                    keys[pos] = ((u64)sbits[r] << 32) | (u64)(0xFFFFFFFFu - (u32)r);
            }
        }
        __syncthreads();
        return s_cc;
    };

    // row-ORDERED emit of {bits == v, row >= rowStart} (rare path: exact tie mass);
    // emits up to capN into keys[pos0..]; returns resume row (N_ROIS = exhausted)
    auto emitEq = [&](u32 v, int rowStart, int pos0, int capN, int* emittedOut) -> int {
        int run = 0, resume = N_ROIS;
        for (int r0 = 0; r0 < N_ROIS; r0 += BLOCKA) {
            if (r0 + BLOCKA <= rowStart) continue;       // uniform skip
            int r = r0 + tid;
            bool pred = (r < N_ROIS) && (r >= rowStart) && (sbits[r] == v);
            u64 ball = __ballot(pred);
            if (lane == 0) s_wofs[wid] = __popcll(ball);
            __syncthreads();
            if (tid == 0) {
                int acc = 0;
                for (int w = 0; w < NWAVES; ++w) { int cw = s_wofs[w]; s_wofs[w] = acc; acc += cw; }
                s_wofs[NWAVES] = acc; s_resume = N_ROIS;
            }
            __syncthreads();
            int tot = s_wofs[NWAVES];
            if (pred) {
                int idx = run + s_wofs[wid] + (int)__popcll(ball & ((1ull << lane) - 1ull));
                if (idx < capN) keys[pos0 + idx] = ((u64)v << 32) | (u64)(0xFFFFFFFFu - (u32)r);
                else atomicMin(&s_resume, r);
            }
            __syncthreads();
            if (run + tot > capN) {                      // clipped in this chunk
                resume = s_resume < (r0 + BLOCKA) ? s_resume : (r0 + BLOCKA);
                run = capN;
                break;
            }
            run += tot;
        }
        *emittedOut = run;
        return resume;
    };

    // ---- 2. lazy band loop (typical: band 0 only)
    u32 Vhi = 0x80000000u;      // exclusive upper bound of unprocessed values
    int procCnt = 0, knum = 0;
    u32 Vfloor = 0; int eligTotal = 0x7FFFFFFF; bool haveFloor = false;
    u32 eqV = 0; int eqRow = N_ROIS; bool eqPend = false;

    for (int band = 0; band < 64 && knum < POST_TOPN; ++band) {
        int C = 0;
        if (eqPend) {                                    // continue equal-value stream (rare)
            int E; int resume = emitEq(eqV, eqRow, 0, BANDCAP, &E);
            C = E; procCnt += E;
            if (resume >= N_ROIS) { eqPend = false; Vhi = eqV; }
            eqRow = resume;
            if (C == 0) { if (eqPend) break; else continue; }
        } else {
            if (band >= 1) {                             // rare: need the exact 6000-floor
                if (!haveFloor) {
                    u32 V = 0; int cv = N_ROIS;
                    for (int b = 30; b >= 0; --b) {
                        u32 cd = V | (1u << b);
                        int c2 = count_ge(cd);
                        if (c2 >= PRE_TOPN) { V = cd; cv = c2; }
                    }
                    Vfloor = V; eligTotal = cv; haveFloor = true;
                }
                if (procCnt >= eligTotal) break;         // all eligible processed
            }
            int target = procCnt + BANDK;
            int capAbs = procCnt + BANDCAP;
            u32 V = 0; int cv = N_ROIS;
            for (int b = 30; b >= 16; --b) {             // 15-round 16-bit-granular select
                u32 cd = V | (1u << b);
                int c2 = count_ge(cd);
                if (c2 >= target) { V = cd; cv = c2; }
            }
            for (int b = 15; b >= 0 && cv > capAbs; --b) {  // rare refinement
                u32 cd = V | (1u << b);
                int c2 = count_ge(cd);
                if (c2 >= target) { V = cd; cv = c2; }
            }
            if (haveFloor && V < Vfloor) { V = Vfloor; cv = eligTotal; }
            if (cv > capAbs) {                           // exact-duplicate mass: gt + eq stream
                int ngt = compactRange(V + 1, Vhi, 0);
                int E; int resume = emitEq(V, 0, ngt, BANDCAP - ngt, &E);
                C = ngt + E; procCnt += C;
                eqV = V; eqRow = resume; eqPend = (resume < N_ROIS);
                if (!eqPend) Vhi = V;
            } else {
                C = compactRange(V, Vhi, 0);
                procCnt = cv; Vhi = V;
            }
            if (C <= 0) continue;
        }

        // ---- 3. exact rank by pairwise comparison (replaces bitonic sort; keys unique)
        for (int q = tid; q < BANDCAP; q += BLOCKA) rnk[q] = 0;
        __syncthreads();
        {
            int q0 = tid >> 1, par = tid & 1;
            for (int q = q0; q < C; q += BLOCKA / 2) {
                u64 kq = keys[q]; int partial = 0;
                for (int p = par; p < C; p += 2) partial += (keys[p] > kq) ? 1 : 0;
                atomicAdd(&rnk[q], (u32)partial);
            }
        }
        __syncthreads();
        // scatter into sorted order + gather candidate boxes
        for (int q = tid; q < C; q += BLOCKA) {
            u64 kq = keys[q];
            u32 pos = rnk[q];
            u32 r = 0xFFFFFFFFu - (u32)kq;
            sidx[pos] = r;
            sbox[pos] = *(const float4*)(boxes + ((size_t)r * N_CLS + c) * 4);
        }
        __syncthreads();

        // ---- 4. chunked greedy: phase A (vs kept) -> pair matrix + rz -> batched sweep
        for (int base = 0; base < C && knum < POST_TOPN; base += CHUNK) {
            int chunkN = (C - base) < CHUNK ? (C - base) : CHUNK;
            int knum0 = knum;

            if (tid < CHUNK) {          // phase A (knum0==0 on the common path -> trivial)
                bool al = false;
                if (tid < chunkN) {
                    al = true;
                    float4 bq = sbox[base + tid];
                    for (int j = 0; j < knum0; ++j)
                        if (suppresses(kbox[j], bq)) { al = false; break; }
                }
                u64 ball = __ballot(al);
                if (lane == 0) { s_alive[wid * 2] = (u32)ball; s_alive[wid * 2 + 1] = (u32)(ball >> 32); }
            }
            if (tid < CWORDS) s_rz[tid] = 0;
            for (int w = tid; w < CHUNK * CWORDS; w += BLOCKA) supp[w] = 0;
            __syncthreads();

            {   // build "p suppresses q" (p<q, both alive); 2 threads per row q; broadcast reads
                int q0 = tid >> 1, par = tid & 1;
                for (int q = q0; q < chunkN; q += BLOCKA / 2) {
                    if (!((s_alive[q >> 5] >> (q & 31)) & 1u)) continue;
                    float4 bq = sbox[base + q];
                    for (int p = par; p < q; p += 2) {
                        if (!((s_alive[p >> 5] >> (p & 31)) & 1u)) continue;
                        if (suppresses(sbox[base + p], bq)) {
                            atomicOr(&supp[p * CWORDS + (q >> 5)], 1u << (q & 31));
                            atomicOr(&s_rz[p >> 5], 1u << (p & 31));
                        }
                    }
                }
            }
            __syncthreads();

            // sweep (wave 0): batch-keep non-suppressing candidates; serial work only for rz picks
            if (wid == 0) {
                u32 aw  = (lane < CWORDS) ? s_alive[lane] : 0u;
                u32 rzw = (lane < CWORDS) ? s_rz[lane] : 0u;
                const int budget = POST_TOPN - knum0;    // >= 1
                int truncTo = -1;
                while (true) {
                    u32 pz = aw & rzw;
                    u64 bal = __ballot(pz != 0u);
                    if (!bal) break;
                    int pl = __ffsll(bal) - 1;
                    u32 wv = __shfl(pz, pl);
                    int b = __ffs(wv) - 1;
                    int p = (pl << 5) + b;
                    int cb = (lane < pl) ? __popc(aw) : ((lane == pl) ? __popc(aw & ((1u << b) - 1u)) : 0);
                    for (int off = 32; off; off >>= 1) cb += __shfl_down(cb, off);
                    int before = __shfl(cb, 0);
                    if (before >= budget) { truncTo = budget; break; }
                    int widx = (lane < CWORDS) ? lane : 0;
                    u32 row = supp[p * CWORDS + widx];
                    if (lane < CWORDS) aw &= ~row;       // suppress later chunk-mates
                    if (lane == pl) { aw |= (1u << b); rzw &= ~(1u << b); }
                    if (before + 1 >= budget) { truncTo = budget; break; }
                }
                if (truncTo < 0) {
                    int pcT = __popc(aw);
                    for (int off = 32; off; off >>= 1) pcT += __shfl_down(pcT, off);
                    if (__shfl(pcT, 0) > budget) truncTo = budget;
                }
                if (truncTo >= 0) {                      // keep only first truncTo alive bits
                    int pcf = __popc(aw);
                    int inc = pcf;
                    for (int off = 1; off < 64; off <<= 1) { int o = __shfl_up(inc, off); if (lane >= off) inc += o; }
                    int ex = inc - pcf;
                    int need = truncTo - ex;
                    if (need <= 0) aw = 0;
                    else if (need < pcf) {
                        while (__popc(aw) > need) aw &= ~(1u << (31 - __clz(aw)));
                    }
                }
                if (lane < CWORDS) s_alive[lane] = aw;
                int pcf2 = __popc(aw);
                int inc2 = pcf2;
                for (int off = 1; off < 64; off <<= 1) { int o = __shfl_up(inc2, off); if (lane >= off) inc2 += o; }
                if (lane < CWORDS) s_wpre[lane] = inc2 - pcf2;
                int totF = __shfl(inc2, 63);
                if (lane == 0) s_nk = knum0 + totF;
            }
            __syncthreads();

            // commit: alive mask IS the kept set for this chunk
            if (tid < CHUNK) {
                int w = tid >> 5, b = tid & 31;
                u32 word = s_alive[w];
                if ((word >> b) & 1u) {
                    int rank = knum0 + s_wpre[w] + __popc(word & ((1u << b) - 1u));
                    int q = base + tid;
                    u32 r = sidx[q];
                    u32 sb = sbits[r];
                    kbox[rank] = sbox[q];
                    dists[(size_t)r * N_CLS + c] = __uint_as_float(sb);
                    atomicMax(rowkey + r, ((u64)sb << 32) | (u64)(0xFFFFFFFFu - (u32)c));
                }
            }
            __syncthreads();
            knum = s_nk;
        }
    }
}

// fused: scores transpose (coalesced column reads for nms) + zero dists/rowkey
__global__ __launch_bounds__(1024)
void transpose_zero_kernel(const float* __restrict__ in, float* __restrict__ outT,
                           float* __restrict__ dists, u64* __restrict__ rowkey, int useT)
{
    __shared__ float tile[32][33];
    if (useT) {
        int tx = threadIdx.x & 31, ty = threadIdx.x >> 5;
        int rb = blockIdx.x * 32, cb = blockIdx.y * 32;
        int r = rb + ty, cc = cb + tx;
        tile[ty][tx] = (r < N_ROIS && cc < N_CLS) ? in[(size_t)r * N_CLS + cc] : 0.f;
        __syncthreads();
        int oc = cb + ty, orr = rb + tx;
        if (oc < N_CLS) outT[(size_t)oc * TROWS + orr] = tile[tx][ty];
    }
    int bid = blockIdx.y * gridDim.x + blockIdx.x;   // 0..1599
    int flat = bid * 1024 + threadIdx.x;             // 0..1638399 >= 1510000
    if (flat < N_ROIS * N_CLS) dists[flat] = 0.f;
    if (flat < N_ROIS) rowkey[flat] = 0ull;
}

// top-64: 15-round bit-greedy select + compact + register rank (no serial argmaxes)
__global__ __launch_bounds__(BLOCKA)
void topk_kernel(const u64* __restrict__ rowkey, float* __restrict__ out)
{
    __shared__ u32 shi[N_ROIS];
    __shared__ int s_cnts[32];
    __shared__ int s_cc;
    __shared__ u64 cand[192];
    __shared__ int s_wofs[NWAVES + 1];
    const int tid = threadIdx.x, lane = tid & 63, wid = tid >> 6;

    if (tid < 32) s_cnts[tid] = 0;
    if (tid == 0) s_cc = 0;
    if (tid < 192) cand[tid] = 0;
    for (int i = tid; i < N_ROIS; i += BLOCKA) {
        u64 rk = rowkey[i];
        u32 hb = (u32)(rk >> 32);
        shi[i] = (__uint_as_float(hb) > SCORE_TH) ? hb : 0u;   // invalid rows -> 0
    }
    __syncthreads();

    int slot = 0;
    auto count_ge = [&](u32 v) -> int {
        int cnt = 0;
        const u64* s2 = (const u64*)shi;
        for (int r2 = tid; r2 < N_ROIS / 2; r2 += BLOCKA) {
            u64 two = s2[r2];
            cnt += ((u32)two >= v) ? 1 : 0;
            cnt += ((u32)(two >> 32) >= v) ? 1 : 0;
        }
        for (int off = 32; off; off >>= 1) cnt += __shfl_down(cnt, off);
        if (lane == 0 && cnt) atomicAdd(&s_cnts[slot & 31], cnt);
        __syncthreads();
        int total = s_cnts[slot & 31];
        if (tid == 0) s_cnts[(slot + 16) & 31] = 0;
        ++slot;
        return total;
    };

    const int cap = 128;
    u32 V = 0; int cv = N_ROIS;
    for (int b = 30; b >= 16; --b) {
        u32 cd = V | (1u << b);
        int c2 = count_ge(cd);
        if (c2 >= MAX_PER) { V = cd; cv = c2; }
    }
    for (int b = 15; b >= 0 && cv > cap; --b) {   // rare refinement
        u32 cd = V | (1u << b);
        int c2 = count_ge(cd);
        if (c2 >= MAX_PER) { V = cd; cv = c2; }
    }
    if (V == 0) { V = 1; cv = count_ge(1); }      // fewer than 64 valid rows
    int C = 0;
    if (cv > cap) {
        // exact-duplicate fallback: strictly-greater part + lowest-row equal fill to 64
        if (tid == 0) s_cc = 0;
        __syncthreads();
        for (int i = tid; i < TROWS; i += BLOCKA) {
            bool pred = (i < N_ROIS) && (shi[i] >= V + 1);
            u64 ball = __ballot(pred);
            int bpos = 0, bcnt = __popcll(ball);
            if (lane == 0 && bcnt) bpos = atomicAdd(&s_cc, bcnt);
            bpos = __shfl(bpos, 0);
            if (pred) {
                int pos = bpos + (int)__popcll(ball & ((1ull << lane) - 1ull));
                if (pos < cap) cand[pos] = ((u64)shi[i] << 32) | (u64)(0xFFFFFFFFu - (u32)i);
            }
        }
        __syncthreads();
        int ngt = s_cc; if (ngt > cap) ngt = cap;
        int need = MAX_PER - ngt;                  // > 0 here
        int run = 0;
        for (int r0 = 0; r0 < N_ROIS && run < need; r0 += BLOCKA) {
            int r = r0 + tid;
            bool pred = (r < N_ROIS) && (shi[r] == V);
            u64 ball = __ballot(pred);
            if (lane == 0) s_wofs[wid] = __popcll(ball);
            __syncthreads();
            if (tid == 0) {
                int acc = 0;
                for (int w = 0; w < NWAVES; ++w) { int cw = s_wofs[w]; s_wofs[w] = acc; acc += cw; }
                s_wofs[NWAVES] = acc;
            }
            __syncthreads();
            int tot = s_wofs[NWAVES];
            if (pred) {
                int idx = run + s_wofs[wid] + (int)__popcll(ball & ((1ull << lane) - 1ull));
                if (idx < need) cand[ngt + idx] = ((u64)V << 32) | (u64)(0xFFFFFFFFu - (u32)r);
            }
            __syncthreads();
            run += tot;
        }
        C = ngt + (run < need ? run : need);
    } else {
        if (tid == 0) s_cc = 0;
        __syncthreads();
        for (int i = tid; i < TROWS; i += BLOCKA) {
            bool pred = (i < N_ROIS) && (shi[i] >= V);
            u64 ball = __ballot(pred);
            int bpos = 0, bcnt = __popcll(ball);
            if (lane == 0 && bcnt) bpos = atomicAdd(&s_cc, bcnt);
            bpos = __shfl(bpos, 0);
            if (pred) {
                int pos = bpos + (int)__popcll(ball & ((1ull << lane) - 1ull));
                if (pos < cap) cand[pos] = ((u64)shi[i] << 32) | (u64)(0xFFFFFFFFu - (u32)i);
            }
        }
        __syncthreads();
        C = s_cc; if (C > cap) C = cap;
    }

    float* out_s = out + (size_t)N_ROIS * N_CLS;
    float* out_i = out_s + MAX_PER;
    float* out_l = out_i + MAX_PER;

    int myrank = -1; u64 myk = 0;
    if (tid < C) {
        myk = cand[tid];
        myrank = 0;
        for (int p = 0; p < C; ++p) myrank += (cand[p] > myk) ? 1 : 0;   // keys unique
    }
    if (tid < MAX_PER) { out_s[tid] = 0.f; out_i[tid] = -1.f; out_l[tid] = -1.f; }
    __syncthreads();
    if (tid < C && myrank < MAX_PER) {
        u32 r = 0xFFFFFFFFu - (u32)myk;
        out_s[myrank] = __uint_as_float((u32)(myk >> 32));
        out_i[myrank] = (float)r;
        out_l[myrank] = (float)(0xFFFFFFFFu - (u32)rowkey[r]);   // label from rowkey low word
    }
}

extern "C" void kernel_launch(void* const* d_in, const int* in_sizes, int n_in,
                              void* d_out, int out_size, void* d_ws, size_t ws_size,
                              hipStream_t stream)
{
    const float* scores = (const float*)d_in[0];  // [10000, 151] f32
    const float* boxes  = (const float*)d_in[1];  // [10000, 151, 4] f32
    float* out = (float*)d_out;                   // dists[1510000] | scores[64] | inds[64] | labels[64]
    u64* rowkey = (u64*)d_ws;                     // [10000] packed (scorebits<<32)|~class

    size_t needT = 80000 + (size_t)N_CLS * TROWS * sizeof(float);
    int useT = (ws_size >= needT) ? 1 : 0;
    float* scoresT = (float*)((char*)d_ws + 80000);

    (void)hipFuncSetAttribute((const void*)nms_kernel,
                              hipFuncAttributeMaxDynamicSharedMemorySize, SMEM_BYTES);

    transpose_zero_kernel<<<dim3(320, 5), 1024, 0, stream>>>(scores, scoresT, out, rowkey, useT);
    nms_kernel<<<N_CLS - 1, BLOCKA, SMEM_BYTES, stream>>>(scores, scoresT, boxes, out, rowkey, useT);
    topk_kernel<<<1, BLOCKA, 0, stream>>>(rowkey, out);
}